// Round 2
// baseline (137.439 us; speedup 1.0000x reference)
//
#include <hip/hip_runtime.h>
#include <cmath>

// PillarFeatureNet fused: augment(10ch) -> linear(64) -> BN -> exact GELU -> max over points.
// R1 (55.4us, VALU-bound 77%): dynamic per-point LDS loop stalled on lgkmcnt each iter.
// R2 changes: SoA LDS + v_pk_fma_f32 (2 points/inst), neutral-fill masked slots with a
// copy of point 0 (no per-point cndmask, chunks of 8 safe to over-read), max3/min3
// accumulators, rcp instead of IEEE div. Mean still sums ALL 32 raw rows (ref semantics).

typedef float v2f __attribute__((ext_vector_type(2)));

__device__ __forceinline__ float gelu_exact(float x) {
    return 0.5f * x * (1.0f + erff(x * 0.70710678118654752440f));
}

// R: LDS region [4][32] = x[32] y[32] z[32] w[32] for one pillar (neutral-filled).
// Processes ceil(n/8)*8 points; padded slots hold copies of point 0 (harmless for minmax).
__device__ __forceinline__ void pillar_minmax(const float* __restrict__ R, int n,
                                              v2f a0, v2f a1, v2f a2, v2f a3, v2f cc,
                                              float& oMax, float& oMin)
{
    float vmx0 = -INFINITY, vmx1 = -INFINITY, vmx2 = -INFINITY, vmx3 = -INFINITY;
    float vmn0 =  INFINITY, vmn1 =  INFINITY, vmn2 =  INFINITY, vmn3 =  INFINITY;
    const int t = (n + 7) >> 3;             // 1..4 chunks, wave-uniform
    for (int c = 0; c < t; ++c) {
        const float4* px = (const float4*)(R +   0 + c * 8);
        const float4* py = (const float4*)(R +  32 + c * 8);
        const float4* pz = (const float4*)(R +  64 + c * 8);
        const float4* pw = (const float4*)(R +  96 + c * 8);
        // 8 broadcast ds_read_b128, one waitcnt batch per chunk
        float4 xa = px[0], xb = px[1];
        float4 ya = py[0], yb = py[1];
        float4 za = pz[0], zb = pz[1];
        float4 wa = pw[0], wb = pw[1];
        v2f X0 = {xa.x, xa.y}, X1 = {xa.z, xa.w}, X2 = {xb.x, xb.y}, X3 = {xb.z, xb.w};
        v2f Y0 = {ya.x, ya.y}, Y1 = {ya.z, ya.w}, Y2 = {yb.x, yb.y}, Y3 = {yb.z, yb.w};
        v2f Z0 = {za.x, za.y}, Z1 = {za.z, za.w}, Z2 = {zb.x, zb.y}, Z3 = {zb.z, zb.w};
        v2f W0 = {wa.x, wa.y}, W1 = {wa.z, wa.w}, W2 = {wb.x, wb.y}, W3 = {wb.z, wb.w};
        v2f y0 = __builtin_elementwise_fma(X0, a0, __builtin_elementwise_fma(Y0, a1,
                 __builtin_elementwise_fma(Z0, a2, __builtin_elementwise_fma(W0, a3, cc))));
        v2f y1 = __builtin_elementwise_fma(X1, a0, __builtin_elementwise_fma(Y1, a1,
                 __builtin_elementwise_fma(Z1, a2, __builtin_elementwise_fma(W1, a3, cc))));
        v2f y2 = __builtin_elementwise_fma(X2, a0, __builtin_elementwise_fma(Y2, a1,
                 __builtin_elementwise_fma(Z2, a2, __builtin_elementwise_fma(W2, a3, cc))));
        v2f y3 = __builtin_elementwise_fma(X3, a0, __builtin_elementwise_fma(Y3, a1,
                 __builtin_elementwise_fma(Z3, a2, __builtin_elementwise_fma(W3, a3, cc))));
        vmx0 = fmaxf(fmaxf(y0.x, y0.y), vmx0);  vmn0 = fminf(fminf(y0.x, y0.y), vmn0);
        vmx1 = fmaxf(fmaxf(y1.x, y1.y), vmx1);  vmn1 = fminf(fminf(y1.x, y1.y), vmn1);
        vmx2 = fmaxf(fmaxf(y2.x, y2.y), vmx2);  vmn2 = fminf(fminf(y2.x, y2.y), vmn2);
        vmx3 = fmaxf(fmaxf(y3.x, y3.y), vmx3);  vmn3 = fminf(fminf(y3.x, y3.y), vmn3);
    }
    oMax = fmaxf(fmaxf(vmx0, vmx1), fmaxf(vmx2, vmx3));
    oMin = fminf(fminf(vmn0, vmn1), fminf(vmn2, vmn3));
}

__global__ __launch_bounds__(256) void pfn_kernel(
    const float* __restrict__ features,   // (N, 32, 4)
    const int*   __restrict__ num_points, // (N,)
    const int*   __restrict__ coors,      // (N, 4)
    const float* __restrict__ W,          // (64, 10)
    const float* __restrict__ gamma,
    const float* __restrict__ beta,
    const float* __restrict__ rmean,
    const float* __restrict__ rvar,
    float*       __restrict__ out,        // (N, 64)
    int nTotal)
{
    // per-wave slot: [2 pillars][4 comps][32 points], SoA
    __shared__ float lds[4][2 * 4 * 32];

    const int lane = threadIdx.x & 63;
    const int wid  = threadIdx.x >> 6;
    const int waveGlobal = blockIdx.x * 4 + wid;
    const int waveCount  = gridDim.x * 4;
    const int nPairs = (nTotal + 1) >> 1;
    float* slot = &lds[wid][0];

    // lane == output channel o
    const int o = lane;
    const float w0 = W[o*10+0], w1 = W[o*10+1], w2 = W[o*10+2], w3 = W[o*10+3],
                w4 = W[o*10+4], w5 = W[o*10+5], w6 = W[o*10+6], w7 = W[o*10+7],
                w8 = W[o*10+8], w9 = W[o*10+9];
    const float a = gamma[o] / sqrtf(rvar[o] + 1e-3f);
    const float b = fmaf(-rmean[o], a, beta[o]);      // BN(0): masked rows' y
    const float A0s = a*(w0+w4+w7), A1s = a*(w1+w5+w8), A2s = a*(w2+w6+w9), A3s = a*w3;
    const v2f a0 = {A0s, A0s}, a1 = {A1s, A1s}, a2 = {A2s, A2s}, a3 = {A3s, A3s};

    for (int p = waveGlobal; p < nPairs; p += waveCount) {
        const int iA = 2 * p;
        const bool hasB = (2 * p + 1 < nTotal);
        const int iB = hasB ? (2 * p + 1) : (nTotal - 1);

        // ---- phase 1: coalesced 1KB load, mean over ALL 32 raw rows ----
        const float4* fb = reinterpret_cast<const float4*>(features) + (size_t)p * 64;
        const float4 f = fb[lane];             // lane l -> pillar (l>=32), point (l&31)

        float sx = f.x, sy = f.y, sz = f.z;
        #pragma unroll
        for (int d = 1; d < 32; d <<= 1) {
            sx += __shfl_xor(sx, d);
            sy += __shfl_xor(sy, d);
            sz += __shfl_xor(sz, d);
        }
        const float tx = __shfl_xor(sx, 32), ty = __shfl_xor(sy, 32), tz = __shfl_xor(sz, 32);

        const int nA = num_points[iA];
        const int nB = num_points[iB];
        const int4 cA = reinterpret_cast<const int4*>(coors)[iA];
        const int4 cB = reinterpret_cast<const int4*>(coors)[iB];

        // neutral-fill: masked slots get a copy of own pillar's point 0
        const int m = lane & 31;
        const int nOwn = (lane < 32) ? nA : nB;
        const int src = lane & 32;                   // lane of point 0 in own half
        const float f0x = __shfl(f.x, src), f0y = __shfl(f.y, src),
                    f0z = __shfl(f.z, src), f0w = __shfl(f.w, src);
        const bool valid = m < nOwn;
        const int rbase = (lane >> 5) * 128 + m;     // pillar*128 + comp*32 + m
        slot[rbase +  0] = valid ? f.x : f0x;        // 2-way bank alias = free
        slot[rbase + 32] = valid ? f.y : f0y;
        slot[rbase + 64] = valid ? f.z : f0z;
        slot[rbase + 96] = valid ? f.w : f0w;

        const bool lo = (lane < 32);
        const float sAx = lo ? sx : tx, sAy = lo ? sy : ty, sAz = lo ? sz : tz;
        const float sBx = lo ? tx : sx, sBy = lo ? ty : sy, sBz = lo ? tz : sz;

        // mean = sum(all 32)/n ; rcp is ~1ulp, fine at this tolerance
        const float rcA = __builtin_amdgcn_rcpf((float)nA);
        const float rcB = __builtin_amdgcn_rcpf((float)nB);
        const float mAx = sAx * rcA, mAy = sAy * rcA, mAz = sAz * rcA;
        const float mBx = sBx * rcB, mBy = sBy * rcB, mBz = sBz * rcB;

        // voxel centers: cx=coors[:,2], cy=coors[:,1], cz=coors[:,0]
        const float ccxA = fmaf((float)cA.z, 0.2f,   0.1f);
        const float ccyA = fmaf((float)cA.y, 0.2f, -39.9f);
        const float cczA = fmaf((float)cA.x, 4.0f,  -1.0f);
        const float ccxB = fmaf((float)cB.z, 0.2f,   0.1f);
        const float ccyB = fmaf((float)cB.y, 0.2f, -39.9f);
        const float cczB = fmaf((float)cB.x, 4.0f,  -1.0f);

        const float KA = -(mAx*w4 + mAy*w5 + mAz*w6 + ccxA*w7 + ccyA*w8 + cczA*w9);
        const float KB = -(mBx*w4 + mBy*w5 + mBz*w6 + ccxB*w7 + ccyB*w8 + cczB*w9);
        const float CA = fmaf(a, KA, b);
        const float CB = fmaf(a, KB, b);

        // intra-wave LDS RAW: DS pipe is in-order per wave; fence compiler + drain lgkm
        __asm__ volatile("s_waitcnt lgkmcnt(0)" ::: "memory");

        // ---- phase 2: packed dot + minmax ----
        float vmaxA, vminA, vmaxB, vminB;
        pillar_minmax(slot,       nA, a0, a1, a2, a3, (v2f){CA, CA}, vmaxA, vminA);
        pillar_minmax(slot + 128, nB, a0, a1, a2, a3, (v2f){CB, CB}, vmaxB, vminB);

        if (nA < 32) { vmaxA = fmaxf(vmaxA, b); vminA = fminf(vminA, b); }
        if (nB < 32) { vmaxB = fmaxf(vmaxB, b); vminB = fminf(vminB, b); }

        // gelu valley: max over set attained at pre-activation min or max (2 erfs)
        const float rA = fmaxf(gelu_exact(vmaxA), gelu_exact(vminA));
        const float rB = fmaxf(gelu_exact(vmaxB), gelu_exact(vminB));

        out[(size_t)iA * 64 + o] = rA;
        if (hasB) out[(size_t)iB * 64 + o] = rB;
    }
}

extern "C" void kernel_launch(void* const* d_in, const int* in_sizes, int n_in,
                              void* d_out, int out_size, void* d_ws, size_t ws_size,
                              hipStream_t stream) {
    const float* features   = (const float*)d_in[0];
    const int*   num_points = (const int*)  d_in[1];
    const int*   coors      = (const int*)  d_in[2];
    const float* W          = (const float*)d_in[3];
    const float* gamma      = (const float*)d_in[4];
    const float* beta       = (const float*)d_in[5];
    const float* rmean      = (const float*)d_in[6];
    const float* rvar       = (const float*)d_in[7];
    float* out = (float*)d_out;

    const int nTotal = in_sizes[1];  // N pillars

    // 2048 blocks x 4 waves = 8192 waves (32/CU capacity), ~6 pairs per wave
    pfn_kernel<<<2048, 256, 0, stream>>>(features, num_points, coors, W,
                                         gamma, beta, rmean, rvar, out, nTotal);
}